// Round 7
// baseline (694.618 us; speedup 1.0000x reference)
//
#include <hip/hip_runtime.h>
#include <hip/hip_bf16.h>
#include <cmath>

using bf16 = __hip_bfloat16;
typedef _Float16 f16x8 __attribute__((ext_vector_type(8)));
typedef float f32x16 __attribute__((ext_vector_type(16)));

#define GRIDN 512   // 256 CUs * 2 blocks/CU — co-residency with wide margin
                    // (LDS 2*43.5KB=87 <= 160KB/CU, VGPR cap 256, 8 waves/CU)

// Load element i of an EXTERNAL input whose dtype is decided by flag f:
// f=1 -> fp32, f=0 -> bf16. Element-index based so pointer math is dtype-free.
__device__ __forceinline__ float ldin(const void* p, size_t i, int f) {
    return f ? ((const float*)p)[i] : __bfloat162float(((const bf16*)p)[i]);
}

__device__ __forceinline__ float bfu(unsigned short u) {
    union { unsigned u32; float f; } x; x.u32 = (unsigned)u << 16; return x.f;
}

// Rotation swizzle: chunk c (16B, 8 f16 ch) of pixel X lives at slot
// (c + swq(X)) & 3 within the 64B pixel block. Bank-quad = (4X + slot) mod 8
// covers all 8 quads over 8 consecutive X -> conflict-free b128 reads+writes.
__device__ __forceinline__ int swq(int X) { return (X + (X >> 2)) & 3; }

// ---------------- software grid barrier (replaces cooperative grid.sync) ----
// Monotonic epoch counter in ws[0]; zeroed by a captured hipMemsetAsync before
// each launch. Release: __threadfence() before arrival makes this XCD's L2
// visible (buffer_wbl2); acquire: __threadfence() after the spin invalidates
// stale L1/L2 lines (buffer_inv). One spinner per block, rest wait at the
// block barrier. Deadlock-free iff all GRIDN blocks are co-resident.
__device__ __forceinline__ void gbar(unsigned* cnt, unsigned& ep) {
    __syncthreads();
    if (threadIdx.x == 0) {
        ep += 1;
        __threadfence();
        atomicAdd(cnt, 1u);
        while (atomicAdd(cnt, 0u) < ep * (unsigned)GRIDN)
            __builtin_amdgcn_s_sleep(2);
        __threadfence();
    }
    __syncthreads();
}

// ---------------- per-block dtype detection ---------------------------------
// 4096 samples of even-index ushorts (same indices in every block -> same
// verdict deterministically). fp32 low mantissa halves ~uniform -> E[bad]=32,
// P(bad==0 | fp32) = e^-32 ~ 1e-14. Genuine bf16 normal data: bad==0 always.
__device__ __forceinline__ int detect_f(const void* layers_) {
    const unsigned short* u = (const unsigned short*)layers_;
    __shared__ int s_bad;
    if (threadIdx.x == 0) s_bad = 0;
    __syncthreads();
    int bad = 0;
#pragma unroll
    for (int k = 0; k < 16; ++k) {
        unsigned short v = u[2 * ((threadIdx.x * 16 + k) * 257)];
        int e = (v >> 7) & 0xFF;
        bad += (e == 0xFF || (e == 0 && (v & 0x7FFF))) ? 1 : 0;
    }
    if (bad) atomicAdd(&s_bad, bad);
    __syncthreads();
    return s_bad > 0;
}

// Channel-gather stage of one 32-ch NCHW tensor tile (external dtype) into a
// rotated NHWC f16 LDS plane. Fixed 6-trip unrolled loop (guard only on the
// tail) so many jobs' loads stay in flight (MLP).
__device__ __forceinline__ void stage_nchw_g(char* lds, const void* src,
                                             size_t base_elem, int f, int tid,
                                             int x0g, int y0g) {
#pragma unroll
    for (int it = 0; it < 6; ++it) {
        int job = tid + it * 256;
        if (it < 5 || job < 1360) {                 // 1360 = 4c * 10rows * 34X
            int c = job / 340, rest = job - c * 340;
            int row = rest / 34, X = rest - row * 34;
            int gy = y0g - 1 + row, gx = x0g - 1 + X;
            union { _Float16 h[8]; uint4 v; } pk;
            if (gy >= 0 && gy < 128 && gx >= 0 && gx < 128) {
                size_t e0 = base_elem + (size_t)(c * 8) * 16384 + (size_t)gy * 128 + gx;
                if (f) {
#pragma unroll
                    for (int j = 0; j < 8; ++j)
                        pk.h[j] = (_Float16)(((const float*)src)[e0 + (size_t)j * 16384]);
                } else {
#pragma unroll
                    for (int j = 0; j < 8; ++j)
                        pk.h[j] = (_Float16)bfu(((const unsigned short*)src)[e0 + (size_t)j * 16384]);
                }
            } else {
                pk.v = make_uint4(0u, 0u, 0u, 0u);
            }
            int slot = (c + swq(X)) & 3;
            *(uint4*)(lds + row * 2176 + (X << 6) + (slot << 4)) = pk.v;
        }
    }
}

// Stage NHWC f16 tile (internal scratch): linear b128 LDS writes, source chunk
// chosen by the inverse rotation. Fixed 6-trip unrolled loop as above.
__device__ __forceinline__ void stage_nhwc(char* lds, const _Float16* xh, int tid,
                                           int b, int x0g, int y0g) {
#pragma unroll
    for (int it = 0; it < 6; ++it) {
        int q = tid + it * 256;
        if (it < 5 || q < 1360) {                   // 340 px * 4 slots
            int p = q >> 2, s = q & 3;
            int row = p / 34, X = p - row * 34;
            int c = (s - swq(X)) & 3;               // inverse rotation
            int gy = y0g - 1 + row, gx = x0g - 1 + X;
            uint4 v = {0u, 0u, 0u, 0u};
            if (gy >= 0 && gy < 128 && gx >= 0 && gx < 128)
                v = *(const uint4*)(xh + (((size_t)(b * 128 + gy) * 128 + gx) * 32 + c * 8));
            *(uint4*)(lds + (q << 4)) = v;
        }
    }
}

// Both planes' MFMA accumulation: 4 ic-chunks of 16 (kc 0,1 -> plane A at
// lds+0; kc 2,3 -> plane B at lds+21760), 9 taps each.
__device__ __forceinline__ void conv_both(const char* lds, const _Float16* wseg,
                                          int lane, int wid, int lh,
                                          f32x16& acc0, f32x16& acc1) {
    const int l31 = lane & 31;
#pragma unroll
    for (int kc = 0; kc < 4; ++kc) {
        f16x8 bfr[9];
#pragma unroll
        for (int t = 0; t < 9; ++t)
            bfr[t] = *(const f16x8*)(wseg + (size_t)((kc * 9 + t) * 64 + lane) * 8);
        const char* pl = lds + ((kc & 2) ? 21760 : 0);
        const int chunk = ((kc & 1) << 1) | lh;     // 16B chunk = ic 8*chunk..+7
#pragma unroll
        for (int iy = 0; iy < 4; ++iy) {
            const int rowoff = ((wid << 1) + iy) * 2176;
#pragma unroll
            for (int kx = 0; kx < 3; ++kx) {
                const int X = l31 + kx;
                const int slot = (chunk + swq(X)) & 3;
                const f16x8 a = *(const f16x8*)(pl + rowoff + (X << 6) + (slot << 4));
#pragma unroll
                for (int ky = 0; ky < 3; ++ky) {
                    const int y = iy - ky;
                    if (y == 0)
                        acc0 = __builtin_amdgcn_mfma_f32_32x32x16_f16(a, bfr[ky * 3 + kx], acc0, 0, 0, 0);
                    else if (y == 1)
                        acc1 = __builtin_amdgcn_mfma_f32_32x32x16_f16(a, bfr[ky * 3 + kx], acc1, 0, 0, 0);
                }
            }
        }
    }
}

// Single-plane version for the final conv (32 ic, plane at lds+0).
__device__ __forceinline__ void conv_plane(const char* lds, const _Float16* wseg,
                                           int lane, int wid, int lh,
                                           f32x16& acc0, f32x16& acc1) {
    const int l31 = lane & 31;
#pragma unroll
    for (int kc = 0; kc < 2; ++kc) {
        f16x8 bfr[9];
#pragma unroll
        for (int t = 0; t < 9; ++t)
            bfr[t] = *(const f16x8*)(wseg + (size_t)((kc * 9 + t) * 64 + lane) * 8);
        const int chunk = (kc << 1) | lh;
#pragma unroll
        for (int iy = 0; iy < 4; ++iy) {
            const int rowoff = ((wid << 1) + iy) * 2176;
#pragma unroll
            for (int kx = 0; kx < 3; ++kx) {
                const int X = l31 + kx;
                const int slot = (chunk + swq(X)) & 3;
                const f16x8 a = *(const f16x8*)(lds + rowoff + (X << 6) + (slot << 4));
#pragma unroll
                for (int ky = 0; ky < 3; ++ky) {
                    const int y = iy - ky;
                    if (y == 0)
                        acc0 = __builtin_amdgcn_mfma_f32_32x32x16_f16(a, bfr[ky * 3 + kx], acc0, 0, 0, 0);
                    else if (y == 1)
                        acc1 = __builtin_amdgcn_mfma_f32_32x32x16_f16(a, bfr[ky * 3 + kx], acc1, 0, 0, 0);
                }
            }
        }
    }
}

__device__ __forceinline__ float ftanh(float x) {
    float e = __expf(2.f * x);
    return 1.f - 2.f / (e + 1.f);
}

// ---------------- node conv phase: 1024 tiles grid-strided over GRIDN -------
__device__ __forceinline__ void node_phase(char* lds, const void* xprev,
    int xprev_nchw, int xprev_slice, const void* layers, int skip_slice,
    const _Float16* wl, const float* bias, int f, _Float16* out) {
    const int tid = threadIdx.x;
    const int lane = tid & 63, wid = tid >> 6;
    const int l31 = lane & 31, lh = lane >> 5;
    for (int t = blockIdx.x; t < 1024; t += GRIDN) {
        __syncthreads();                             // LDS reuse guard
        const int x0g = (t & 3) << 5, y0g = ((t >> 2) & 15) << 3, b = t >> 6;

        if (xprev_nchw)
            stage_nchw_g(lds, xprev, (size_t)xprev_slice * 8388608 + (size_t)b * 524288,
                         f, tid, x0g, y0g);
        else
            stage_nhwc(lds, (const _Float16*)xprev, tid, b, x0g, y0g);
        stage_nchw_g(lds + 21760, layers, (size_t)skip_slice * 8388608 + (size_t)b * 524288,
                     f, tid, x0g, y0g);
        __syncthreads();

        f32x16 acc0, acc1;
#pragma unroll
        for (int r = 0; r < 16; ++r) { acc0[r] = 0.f; acc1[r] = 0.f; }
        conv_both(lds, wl, lane, wid, lh, acc0, acc1);
        __syncthreads();                             // reads done; lds reusable

        // epilogue: bias+ReLU -> LDS assembly (80B px stride) -> contiguous
        // uint4 global stores (avoids 3x partial-line write amplification).
        const float bs = bias[l31];
        const int row0 = wid << 1;
#pragma unroll
        for (int r = 0; r < 16; ++r) {
            const int xr = (r & 3) + ((r >> 2) << 3) + (lh << 2);
            *(_Float16*)(lds + (row0 * 32 + xr) * 80 + (l31 << 1)) =
                (_Float16)fmaxf(acc0[r] + bs, 0.f);
            *(_Float16*)(lds + ((row0 + 1) * 32 + xr) * 80 + (l31 << 1)) =
                (_Float16)fmaxf(acc1[r] + bs, 0.f);
        }
        __syncthreads();
        const size_t obase = ((size_t)(b * 128 + y0g) * 128 + x0g) * 32;
#pragma unroll
        for (int it = 0; it < 4; ++it) {
            int g = tid + it * 256;                  // 1024 uint4 chunks
            int prow = g >> 7, inrow = g & 127;
            uint4 v = *(const uint4*)(lds + (prow * 32 + (inrow >> 2)) * 80 + (inrow & 3) * 16);
            *(uint4*)(out + obase + (size_t)prow * 4096 + inrow * 8) = v;
        }
    }
}

// ---------------- final conv phase: 32 -> 8 (oc padded to 32), fast tanh ----
__device__ __forceinline__ void final_phase(char* lds, const _Float16* xin,
                                            const _Float16* wf, const float* fbias,
                                            _Float16* outF) {
    const int tid = threadIdx.x;
    const int lane = tid & 63, wid = tid >> 6;
    const int l31 = lane & 31, lh = lane >> 5;
    for (int t = blockIdx.x; t < 1024; t += GRIDN) {
        __syncthreads();
        const int x0g = (t & 3) << 5, y0g = ((t >> 2) & 15) << 3, b = t >> 6;
        stage_nhwc(lds, xin, tid, b, x0g, y0g);
        __syncthreads();

        f32x16 acc0, acc1;
#pragma unroll
        for (int r = 0; r < 16; ++r) { acc0[r] = 0.f; acc1[r] = 0.f; }
        conv_plane(lds, wf, lane, wid, lh, acc0, acc1);
        __syncthreads();

        const float bs = fbias[l31];
        const int row0 = wid << 1;
        if (l31 < 8) {
#pragma unroll
            for (int r = 0; r < 16; ++r) {
                const int xr = (r & 3) + ((r >> 2) << 3) + (lh << 2);
                *(_Float16*)(lds + (row0 * 32 + xr) * 16 + (l31 << 1)) =
                    (_Float16)ftanh(acc0[r] + bs);
                *(_Float16*)(lds + ((row0 + 1) * 32 + xr) * 16 + (l31 << 1)) =
                    (_Float16)ftanh(acc1[r] + bs);
            }
        }
        __syncthreads();
        {
            int g = tid;                             // 256 uint4 chunks
            uint4 v = *(const uint4*)(lds + g * 16);
            int prow = g >> 5, px = g & 31;
            *(uint4*)(outF + ((size_t)(b * 128 + y0g + prow) * 128 + x0g + px) * 8) = v;
        }
    }
}

// ---------------- upsample phase: depthwise bilinear x2 + ramps -------------
__device__ __forceinline__ void up_phase(const _Float16* F, const float* wf,
                                         int f, void* out) {
    for (int t = blockIdx.x; t < 1024; t += GRIDN) {
        int i = t * 256 + threadIdx.x;
        int qx = i & 127, qy = (i >> 7) & 127, b = i >> 14;

        f16x8 inb[3][3];
#pragma unroll
        for (int jy = 0; jy < 3; ++jy)
#pragma unroll
            for (int jx = 0; jx < 3; ++jx) {
                int iy = qy - 1 + jy, ix = qx - 1 + jx;
                f16x8 v;
#pragma unroll
                for (int c = 0; c < 8; ++c) v[c] = (_Float16)0.f;
                if (iy >= 0 && iy < 128 && ix >= 0 && ix < 128)
                    v = *(const f16x8*)(F + (((size_t)(b * 128 + iy) * 128 + ix) << 3));
                inb[jy][jx] = v;
            }

        float acc[32];                               // [c][dy][dx], static idx
#pragma unroll
        for (int k = 0; k < 32; ++k) acc[k] = 0.f;
#pragma unroll
        for (int ky = 0; ky < 4; ++ky) {
            const int dy = 1 - (ky & 1), jy = 2 - ((ky + 1) >> 1);
#pragma unroll
            for (int kx = 0; kx < 4; ++kx) {
                const int dx = 1 - (kx & 1), jx = 2 - ((kx + 1) >> 1);
                const f16x8 p = inb[jy][jx];
#pragma unroll
                for (int c = 0; c < 8; ++c)
                    acc[c * 4 + dy * 2 + dx] =
                        fmaf((float)p[c], wf[c * 16 + ky * 4 + kx], acc[c * 4 + dy * 2 + dx]);
            }
        }
#pragma unroll
        for (int d = 0; d < 4; ++d) {
            acc[d]     += (float)(2 * qy + (d >> 1)) * (1.0f / 256.0f);  // c0 row ramp
            acc[4 + d] += (float)(2 * qx + (d & 1)) * (1.0f / 256.0f);   // c1 col ramp
        }
#pragma unroll
        for (int c = 0; c < 8; ++c)
#pragma unroll
            for (int dy2 = 0; dy2 < 2; ++dy2) {
                size_t a = ((size_t)(b * 8 + c) * 256 + (qy * 2 + dy2)) * 256 + qx * 2;
                float v0 = acc[c * 4 + dy2 * 2], v1 = acc[c * 4 + dy2 * 2 + 1];
                if (f) {
                    *(float2*)((float*)out + a) = make_float2(v0, v1);
                } else {
                    union { bf16 h; unsigned short u; } u0, u1;
                    u0.h = __float2bfloat16(v0); u1.h = __float2bfloat16(v1);
                    ((unsigned*)out)[a >> 1] = (unsigned)u0.u | ((unsigned)u1.u << 16);
                }
            }
    }
}

// ---------------- the whole net as ONE kernel (software grid barrier) -------
// ws layout (bytes):
//   0      barrier counter (4B, zeroed by captured hipMemsetAsync)
//   160    wpkN  : f16 [lay4][kc4][t9][lane64][e8]          (147456 B)
//   147616 wpkF  : f16 [kc2][t9][lane64][e8]                (18432 B)
//   166048 upwf  : f32 [128]
//   166560 nbias : f32 [4][32]
//   167072 fbias : f32 [32] (oc>=8 -> 0)
//   167424 X     : f16 NHWC scratch buffer (16777216 B)
__global__ __launch_bounds__(256, 2) void mega_kernel(
    const void* __restrict__ layers, const void* __restrict__ nw,
    const void* __restrict__ ng, const void* __restrict__ nbp,
    const void* __restrict__ nm, const void* __restrict__ nv,
    const void* __restrict__ fw, const void* __restrict__ fg,
    const void* __restrict__ fb, const void* __restrict__ fm,
    const void* __restrict__ fv, const void* __restrict__ upw,
    char* __restrict__ ws, void* __restrict__ dout) {
    __shared__ char lds[43520];                 // planeA 0.., planeB 21760..
    unsigned* cnt = (unsigned*)ws;
    unsigned ep = 0;

    const int f = detect_f(layers);             // block-local dtype flag

    _Float16* wpkN = (_Float16*)(ws + 160);
    _Float16* wpkF = (_Float16*)(ws + 147616);
    float* upwf  = (float*)(ws + 166048);
    float* nbias = (float*)(ws + 166560);
    float* fbias = (float*)(ws + 167072);
    _Float16* X  = (_Float16*)(ws + 167424);    // f16 NHWC scratch (ws)
    _Float16* Y  = (_Float16*)dout;             // d_out reused as scratch

    // ---- phase 0: weight/BN pack (fold BN scale into f16 B-fragments) ----
    {
        int i = blockIdx.x * 256 + threadIdx.x;
        if (i < 73728) {
            int e = i & 7, lane = (i >> 3) & 63, rest = i >> 9;  // (lay*4+kc)*9+t
            int t = rest % 9, rest2 = rest / 9;
            int kc = rest2 & 3, lay = rest2 >> 2;
            int oc = lane & 31, ic = kc * 16 + ((lane >> 5) << 3) + e;
            float s = ldin(ng, lay * 32 + oc, f) * rsqrtf(ldin(nv, lay * 32 + oc, f) + 1e-5f);
            float w = ldin(nw, ((size_t)(lay * 32 + oc) * 64 + ic) * 9 + t, f);
            wpkN[i] = (_Float16)(w * s);
        } else if (i < 82944) {
            int j = i - 73728;
            int e = j & 7, lane = (j >> 3) & 63, rest = j >> 9;   // kc*9+t
            int t = rest % 9, kc = rest / 9;
            int oc = lane & 31, ic = kc * 16 + ((lane >> 5) << 3) + e;
            float v = 0.f;
            if (oc < 8) {
                float s = ldin(fg, oc, f) * rsqrtf(ldin(fv, oc, f) + 1e-5f);
                v = ldin(fw, ((size_t)(oc * 32 + ic)) * 9 + t, f) * s;
            }
            wpkF[j] = (_Float16)v;
        } else if (i < 83072) {
            int k = i - 82944;
            upwf[k] = ldin(upw, k, f);
        } else if (i < 83200) {
            int k = i - 83072;
            float s = ldin(ng, k, f) * rsqrtf(ldin(nv, k, f) + 1e-5f);
            nbias[k] = ldin(nbp, k, f) - ldin(nm, k, f) * s;
        } else if (i < 83232) {
            int k = i - 83200;
            float v = 0.f;
            if (k < 8) {
                float s = ldin(fg, k, f) * rsqrtf(ldin(fv, k, f) + 1e-5f);
                v = ldin(fb, k, f) - ldin(fm, k, f) * s;
            }
            fbias[k] = v;
        }
    }
    gbar(cnt, ep);

    // ---- phases 1-4: node convs (concat implicit via two planes) ----
    node_phase(lds, layers, 1, 0, layers, 1, wpkN,         nbias,      f, X);
    gbar(cnt, ep);
    node_phase(lds, X,      0, 0, layers, 2, wpkN + 18432, nbias + 32, f, Y);
    gbar(cnt, ep);
    node_phase(lds, Y,      0, 0, layers, 3, wpkN + 36864, nbias + 64, f, X);
    gbar(cnt, ep);
    node_phase(lds, X,      0, 0, layers, 4, wpkN + 55296, nbias + 96, f, Y);
    gbar(cnt, ep);

    // ---- phase 5: final conv (reads Y, writes NHWC8 f16 into X) ----
    final_phase(lds, Y, wpkF, fbias, X);
    gbar(cnt, ep);

    // ---- phase 6: upsample (reads X, writes full d_out; Y dead) ----
    up_phase(X, upwf, f, dout);
}

extern "C" void kernel_launch(void* const* d_in, const int* in_sizes, int n_in,
                              void* d_out, int out_size, void* d_ws, size_t ws_size,
                              hipStream_t stream) {
    const void* layers = d_in[0];   // [5][16][32][128][128]
    const void* node_w = d_in[1];   // [4][32][64][3][3]
    const void* ng     = d_in[2];
    const void* nb     = d_in[3];
    const void* nm     = d_in[4];
    const void* nv     = d_in[5];
    const void* fw     = d_in[6];   // [8][32][3][3]
    const void* fg     = d_in[7];
    const void* fb     = d_in[8];
    const void* fm     = d_in[9];
    const void* fv     = d_in[10];
    const void* upw    = d_in[11];  // [8][1][4][4]
    char* ws = (char*)d_ws;

    hipMemsetAsync(ws, 0, 16, stream);   // zero barrier counter (capturable)
    mega_kernel<<<dim3(GRIDN), dim3(256), 0, stream>>>(
        layers, node_w, ng, nb, nm, nv, fw, fg, fb, fm, fv, upw, ws, d_out);
}